// Round 15
// baseline (287.694 us; speedup 1.0000x reference)
//
#include <hip/hip_runtime.h>
#include <cmath>

#define NN 50000
#define NE 800000
#define INF_ 128
#define NR 64
#define OF 128
#define TS 256
#define NT ((NN + TS - 1) / TS)  // 196 tiles

__device__ __forceinline__ unsigned short f2bf_rne(float f) {
  unsigned u = __float_as_uint(f);
  u += 0x7FFFu + ((u >> 16) & 1u);  // round-to-nearest-even
  return (unsigned short)(u >> 16);
}
__device__ __forceinline__ float bf2f(unsigned short h) {
  return __uint_as_float(((unsigned)h) << 16);
}

// zero cnt[]; block 0 also computes q3[d] = sum_j W[(256+d),j] * a[j]
__global__ void k_init(const float* __restrict__ W, const float* __restrict__ a,
                       float* __restrict__ q3, int* __restrict__ cnt) {
  int i = blockIdx.x * 256 + threadIdx.x;
  if (i < NN) cnt[i] = 0;
  if (blockIdx.x == 0 && threadIdx.x < NR) {
    const float* row = W + (size_t)(2 * INF_ + threadIdx.x) * OF;
    float acc = 0.f;
    for (int j = 0; j < OF; ++j) acc = fmaf(row[j], a[j], acc);
    q3[threadIdx.x] = acc;
  }
}

// per-node precompute: xw1h = x@W1 (bf16), xw2h = x@W2 (bf16), p1, p2.
// 16 nodes/block (two independent 8-node halves). x-tile stored TRANSPOSED
// in LDS (xsT[k][node], stride 20 words: 16B-aligned float4 rows, 8-way-max
// write banks) so each k-step needs 2 broadcast ds_read_b128 instead of 8
// scalar ds_read_b32 — the scalar form made LDS-issue cycles comparable to
// the 2048 FMA VALU cycles. Fused: src-degree histogram.
__global__ void k_node_pre(const float* __restrict__ x, const float* __restrict__ W,
                           const float* __restrict__ a, const int* __restrict__ ei,
                           unsigned short* __restrict__ xw1h,
                           unsigned short* __restrict__ xw2h,
                           float* __restrict__ p1, float* __restrict__ p2,
                           int* __restrict__ cnt) {
  int tid = threadIdx.x;                 // 0..255
  int gid = blockIdx.x * 256 + tid;      // 0..799999 == edge id
  atomicAdd(cnt + ei[gid], 1);
  __shared__ float xsT[INF_][20];        // [k][node 0..15], padded to 20
  __shared__ float red[2][4][8];
  int half = tid >> 7;                   // 0/1
  int o = tid & 127;
  int nb = blockIdx.x * 16 + half * 8;   // this half's 8 nodes
  for (int t = 0; t < 8; ++t)
    xsT[o][half * 8 + t] = x[(size_t)(nb + t) * INF_ + o];
  __syncthreads();
  float acc1[8] = {0.f, 0.f, 0.f, 0.f, 0.f, 0.f, 0.f, 0.f};
  float acc2[8] = {0.f, 0.f, 0.f, 0.f, 0.f, 0.f, 0.f, 0.f};
  for (int k = 0; k < INF_; ++k) {
    float w1 = W[(size_t)k * OF + o];
    float w2 = W[(size_t)(INF_ + k) * OF + o];
    float4 a0 = *(const float4*)&xsT[k][half * 8];      // wave-uniform b128
    float4 a1 = *(const float4*)&xsT[k][half * 8 + 4];  // broadcast
    acc1[0] = fmaf(a0.x, w1, acc1[0]); acc2[0] = fmaf(a0.x, w2, acc2[0]);
    acc1[1] = fmaf(a0.y, w1, acc1[1]); acc2[1] = fmaf(a0.y, w2, acc2[1]);
    acc1[2] = fmaf(a0.z, w1, acc1[2]); acc2[2] = fmaf(a0.z, w2, acc2[2]);
    acc1[3] = fmaf(a0.w, w1, acc1[3]); acc2[3] = fmaf(a0.w, w2, acc2[3]);
    acc1[4] = fmaf(a1.x, w1, acc1[4]); acc2[4] = fmaf(a1.x, w2, acc2[4]);
    acc1[5] = fmaf(a1.y, w1, acc1[5]); acc2[5] = fmaf(a1.y, w2, acc2[5]);
    acc1[6] = fmaf(a1.z, w1, acc1[6]); acc2[6] = fmaf(a1.z, w2, acc2[6]);
    acc1[7] = fmaf(a1.w, w1, acc1[7]); acc2[7] = fmaf(a1.w, w2, acc2[7]);
  }
  float av = a[o];
  int wvh = (tid >> 6) & 1;  // wave within half
  int ln = tid & 63;
#pragma unroll
  for (int t = 0; t < 8; ++t) {
    xw1h[(size_t)(nb + t) * OF + o] = f2bf_rne(acc1[t]);
    xw2h[(size_t)(nb + t) * OF + o] = f2bf_rne(acc2[t]);
    float v1 = acc1[t] * av, v2 = acc2[t] * av;
    for (int off = 32; off > 0; off >>= 1) {
      v1 += __shfl_down(v1, off, 64);
      v2 += __shfl_down(v2, off, 64);
    }
    if (ln == 0) { red[0][half * 2 + wvh][t] = v1; red[1][half * 2 + wvh][t] = v2; }
  }
  __syncthreads();
  if (tid < 8) {
    p1[blockIdx.x * 16 + tid] = red[0][0][tid] + red[0][1][tid];
    p2[blockIdx.x * 16 + tid] = red[1][0][tid] + red[1][1][tid];
  } else if (tid >= 128 && tid < 136) {
    int t = tid - 128;
    p1[blockIdx.x * 16 + 8 + t] = red[0][2][t] + red[0][3][t];
    p2[blockIdx.x * 16 + 8 + t] = red[1][2][t] + red[1][3][t];
  }
}

// hierarchical scan, phase A: coalesced per-tile exclusive scan + tile sums
__global__ void k_scanA(const int* __restrict__ cnt, int* __restrict__ roff,
                        int* __restrict__ tsum) {
  __shared__ int sh[TS];
  int b = blockIdx.x, t = threadIdx.x;
  int i = b * TS + t;
  int v = (i < NN) ? cnt[i] : 0;
  sh[t] = v;
  __syncthreads();
  for (int off = 1; off < TS; off <<= 1) {
    int u = (t >= off) ? sh[t - off] : 0;
    __syncthreads();
    sh[t] += u;
    __syncthreads();
  }
  if (i < NN) roff[i] = sh[t] - v;  // exclusive within tile
  if (t == TS - 1) tsum[b] = sh[t];
}

// phase B: every block redundantly LDS-scans the 196 tile sums, adds its
// tile offset, and writes roff (+cur copy); last block sets roff[NN]=NE.
__global__ void k_scanB(const int* __restrict__ tsum, int* __restrict__ roff,
                        int* __restrict__ cur) {
  __shared__ int sh[256];
  int b = blockIdx.x, t = threadIdx.x;
  sh[t] = (t < NT) ? tsum[t] : 0;
  __syncthreads();
  for (int off = 1; off < 256; off <<= 1) {
    int u = (t >= off) ? sh[t - off] : 0;
    __syncthreads();
    sh[t] += u;
    __syncthreads();
  }
  int toff = (b == 0) ? 0 : sh[b - 1];
  int i = b * TS + t;
  if (i < NN) {
    int r = roff[i] + toff;
    roff[i] = r;
    cur[i] = r;
  }
  if (b == NT - 1 && t == 0) roff[NN] = NE;
}

// scatter, 16 lanes per edge: d = ete·q3 (16-lane butterfly), lane0 computes
// ev = exp(leaky_relu(p1[src]+p2[dst]+d)) and writes (dst, ev) to the CSR
// slot; all lanes copy the ete row to ete_csr as bf16 (sequential 256B read,
// random 128B-aligned row write).
__global__ void k_scatter(const int* __restrict__ ei, const float* __restrict__ p1,
                          const float* __restrict__ p2, const float* __restrict__ q3,
                          const float* __restrict__ ete, int* __restrict__ cur,
                          unsigned short* __restrict__ ete_csr,
                          int2* __restrict__ dpv) {
  int grp = threadIdx.x >> 4, l16 = threadIdx.x & 15;
  int e = blockIdx.x * 16 + grp;  // grid*16 == NE exactly
  float4 t4 = ((const float4*)(ete + (size_t)e * NR))[l16];
  float4 q4 = ((const float4*)q3)[l16];
  float dd = t4.x * q4.x + t4.y * q4.y + t4.z * q4.z + t4.w * q4.w;
  dd += __shfl_xor(dd, 8, 16);
  dd += __shfl_xor(dd, 4, 16);
  dd += __shfl_xor(dd, 2, 16);
  dd += __shfl_xor(dd, 1, 16);
  int pos = 0;
  if (l16 == 0) {
    int src = ei[e], dst = ei[NE + e];
    pos = atomicAdd(cur + src, 1);
    float v = p1[src] + p2[dst] + dd;
    v = v > 0.f ? v : 0.2f * v;
    dpv[pos] = make_int2(dst, __float_as_int(__expf(v)));
  }
  pos = __shfl(pos, 0, 16);
  ushort4 h;
  h.x = f2bf_rne(t4.x); h.y = f2bf_rne(t4.y);
  h.z = f2bf_rne(t4.z); h.w = f2bf_rne(t4.w);
  *(ushort4*)(ete_csr + (size_t)pos * NR + l16 * 4) = h;
}

// per-node gather: TWO nodes per wave, ZERO cross-lane ops (round-12 lesson).
// Unroll 8 (16 edges / ~48 loads in flight across both streams) to attack
// the latency-bound 2.6 TB/s effective BW; launch_bounds caps VGPR at 128
// so the deeper pipeline cannot spill (round-6 guard: watch WRITE_SIZE).
__global__ void __launch_bounds__(256, 4)
k_gather(const int2* __restrict__ dpv, const int* __restrict__ roff,
         const unsigned short* __restrict__ ete_csr,
         const unsigned short* __restrict__ xw2h,
         unsigned short* __restrict__ gh,
         unsigned* __restrict__ obuf, float* __restrict__ s) {
  int wv = blockIdx.x * 4 + (threadIdx.x >> 6);  // wave id; grid exact
  int nA = wv * 2, nB = nA + 1;
  int l = threadIdx.x & 63;
  int begA = roff[nA], endA = roff[nA + 1], endB = roff[nB + 1];
  float ssA = 0.f, gaA = 0.f, oA0 = 0.f, oA1 = 0.f;
  float ssB = 0.f, gaB = 0.f, oB0 = 0.f, oB1 = 0.f;
  int jbA = begA, jbB = endA;  // begB == endA (CSR contiguity)
  while (jbA < endA || jbB < endB) {
    int mA = endA - jbA; mA = mA < 0 ? 0 : (mA > 64 ? 64 : mA);
    int mB = endB - jbB; mB = mB < 0 ? 0 : (mB > 64 ? 64 : mB);
    int mm = mA > mB ? mA : mB;
    for (int jj = 0; jj < mm; jj += 8) {
#pragma unroll
      for (int q = 0; q < 8; ++q) {
        int rA = jbA + jj + q, rB = jbB + jj + q;
        bool okA = rA < endA, okB = rB < endB;
        int rAc = okA ? rA : 0, rBc = okB ? rB : 0;
        int2 dpA = dpv[rAc];  // wave-uniform address -> 1 transaction
        int2 dpB = dpv[rBc];
        float evA = okA ? __int_as_float(dpA.y) : 0.f;
        float evB = okB ? __int_as_float(dpB.y) : 0.f;
        float tA = bf2f(ete_csr[(size_t)rAc * NR + l]);
        float tB = bf2f(ete_csr[(size_t)rBc * NR + l]);
        unsigned uA = *(const unsigned*)(xw2h + (size_t)dpA.x * OF + 2 * l);
        unsigned uB = *(const unsigned*)(xw2h + (size_t)dpB.x * OF + 2 * l);
        float xA0 = __uint_as_float(uA << 16);
        float xA1 = __uint_as_float(uA & 0xFFFF0000u);
        float xB0 = __uint_as_float(uB << 16);
        float xB1 = __uint_as_float(uB & 0xFFFF0000u);
        ssA += evA;                ssB += evB;
        gaA = fmaf(evA, tA, gaA);  gaB = fmaf(evB, tB, gaB);
        oA0 = fmaf(evA, xA0, oA0); oB0 = fmaf(evB, xB0, oB0);
        oA1 = fmaf(evA, xA1, oA1); oB1 = fmaf(evB, xB1, oB1);
      }
    }
    jbA += 64; jbB += 64;
  }
  float invA = 1.f / (ssA + 1e-16f);
  float invB = 1.f / (ssB + 1e-16f);
  gh[(size_t)nA * NR + l] = f2bf_rne(gaA * invA);
  gh[(size_t)nB * NR + l] = f2bf_rne(gaB * invB);
  obuf[(size_t)nA * NR + l] =
      ((unsigned)f2bf_rne(oA1 * invA) << 16) | (unsigned)f2bf_rne(oA0 * invA);
  obuf[(size_t)nB * NR + l] =
      ((unsigned)f2bf_rne(oB1 * invB) << 16) | (unsigned)f2bf_rne(oB0 * invB);
  if (l == 0) { s[nA] = ssA; s[nB] = ssB; }
}

// finalize: out = elu( sa*xW1 + o + g@W3 ), 8 nodes/block; single fp32 out
// write. Inputs g/xW1/o are bf16.
__global__ void k_final(const unsigned short* __restrict__ xw1h,
                        const unsigned short* __restrict__ gh,
                        const unsigned* __restrict__ obuf,
                        const float* __restrict__ s, const float* __restrict__ W,
                        float* __restrict__ out) {
  __shared__ float gs[8 * NR];
  int nb = blockIdx.x * 8;
  int o = threadIdx.x;  // 0..127
  for (int i = o; i < 8 * NR; i += 128) gs[i] = bf2f(gh[(size_t)nb * NR + i]);
  __syncthreads();
  float acc[8] = {0.f, 0.f, 0.f, 0.f, 0.f, 0.f, 0.f, 0.f};
  for (int d = 0; d < NR; ++d) {
    float w3 = W[(size_t)(2 * INF_ + d) * OF + o];
#pragma unroll
    for (int t = 0; t < 8; ++t) acc[t] = fmaf(gs[t * NR + d], w3, acc[t]);
  }
#pragma unroll
  for (int t = 0; t < 8; ++t) {
    int n = nb + t;
    float sv = s[n];
    float sa = sv > 0.f ? sv / (sv + 1e-16f) : 0.f;
    unsigned ob = obuf[(size_t)n * NR + (o >> 1)];
    float ov = (o & 1) ? __uint_as_float(ob & 0xFFFF0000u)
                       : __uint_as_float(ob << 16);
    float v = fmaf(sa, bf2f(xw1h[(size_t)n * OF + o]), ov + acc[t]);
    out[(size_t)n * OF + o] = v > 0.f ? v : expm1f(v);
  }
}

extern "C" void kernel_launch(void* const* d_in, const int* in_sizes, int n_in,
                              void* d_out, int out_size, void* d_ws, size_t ws_size,
                              hipStream_t stream) {
  const int* ei = (const int*)d_in[0];
  const float* x = (const float*)d_in[1];
  const float* ete = (const float*)d_in[2];
  const float* W = (const float*)d_in[3];
  const float* a = (const float*)d_in[4];
  float* out = (float*)d_out;

  unsigned short* xw1h = (unsigned short*)d_ws;           // N*128 bf16 (12.8 MB)
  unsigned short* xw2h = xw1h + (size_t)NN * OF;          // N*128 bf16 (12.8 MB)
  unsigned short* ete_csr = xw2h + (size_t)NN * OF;       // NE*64 bf16 (102.4 MB)
  int2* dpv = (int2*)(ete_csr + (size_t)NE * NR);         // E x (dst, ev) (6.4 MB, 8B-aligned)
  unsigned short* gh = (unsigned short*)(dpv + NE);       // N*64 bf16 (6.4 MB)
  unsigned* obuf = (unsigned*)(gh + (size_t)NN * NR);     // N*64 packed bf16x2 (12.8 MB)
  float* p1 = (float*)(obuf + (size_t)NN * NR);           // N
  float* p2 = p1 + NN;                                    // N
  float* q3 = p2 + NN;                                    // 64
  int* cnt = (int*)(q3 + NR);                             // N
  int* roff = cnt + NN;                                   // N+1
  int* cur = roff + NN + 1;                               // N
  int* tsum = cur + NN;                                   // 256
  float* s = (float*)(tsum + 256);                        // N
  // total ~155 MB (ws ~819 MB)

  k_init<<<(NN + 255) / 256, 256, 0, stream>>>(W, a, q3, cnt);
  k_node_pre<<<NN / 16, 256, 0, stream>>>(x, W, a, ei, xw1h, xw2h, p1, p2, cnt);
  k_scanA<<<NT, TS, 0, stream>>>(cnt, roff, tsum);
  k_scanB<<<NT, 256, 0, stream>>>(tsum, roff, cur);
  k_scatter<<<NE / 16, 256, 0, stream>>>(ei, p1, p2, q3, ete, cur, ete_csr, dpv);
  k_gather<<<NN / 8, 256, 0, stream>>>(dpv, roff, ete_csr, xw2h, gh, obuf, s);
  k_final<<<NN / 8, 128, 0, stream>>>(xw1h, gh, obuf, s, W, out);
}